// Round 13
// baseline (69.994 us; speedup 1.0000x reference)
//
#include <hip/hip_runtime.h>
#include <hip/hip_bf16.h>

#define NNODES 100000
#define NHE 20000
#define NEDGES 600000

typedef float f32x4 __attribute__((ext_vector_type(4)));
typedef short bf16x8 __attribute__((ext_vector_type(8)));
typedef short bf16x4 __attribute__((ext_vector_type(4)));
typedef int i32x4 __attribute__((ext_vector_type(4)));
typedef unsigned long long u64;

__device__ __forceinline__ unsigned short f2bf(float f) {
    unsigned u = __builtin_bit_cast(unsigned, f);
    u += 0x7fffu + ((u >> 16) & 1u);
    return (unsigned short)(u >> 16);
}
__device__ __forceinline__ float bf2f(unsigned short h) {
    unsigned u = ((unsigned)h) << 16;
    return __builtin_bit_cast(float, u);
}

// k0: zero packed[] with 16B stores (blocks 0..195) + wt = W_f^T bf16 [c][k]
__global__ void k0(u64* __restrict__ packed, const float* __restrict__ Wf,
                   unsigned short* __restrict__ wt) {
    int b = blockIdx.x, t = threadIdx.x;
    if (b < 196) {
        int i = b * 256 + t;
        if (i < NNODES / 2) ((f32x4*)packed)[i] = (f32x4){0.f, 0.f, 0.f, 0.f};
    } else {
        int idx = (b - 196) * 256 + t;
        int k = idx >> 7, c = idx & 127;
        wt[c * 256 + k] = f2bf(Wf[idx]);
    }
}

// k1: fused — blocks 0..585: vectorized scatter (4 edges/thread, 3x int4);
//             blocks 586..898: heo = he_emb @ Wf[0:128] (BM=64, K=128, swapped mfma)
__global__ __launch_bounds__(256) void k1(
    const int* __restrict__ sl, u64* __restrict__ packed,
    const float* __restrict__ he_emb, const unsigned short* __restrict__ wt,
    unsigned short* __restrict__ heo)
{
    int b = blockIdx.x, t = threadIdx.x;
    if (b < 586) {
        int tg = b * 256 + t;
        if (tg < NEDGES / 4) {
            const i32x4* s4 = (const i32x4*)sl;
            i32x4 a = s4[3 * tg], bb = s4[3 * tg + 1], c = s4[3 * tg + 2];
            int e0 = 4 * tg;
            atomicMax(&packed[a[0]], ((u64)(e0 + 1) << 32) | (unsigned)a[2]);
            atomicMax(&packed[a[3]], ((u64)(e0 + 2) << 32) | (unsigned)bb[1]);
            atomicMax(&packed[bb[2]], ((u64)(e0 + 3) << 32) | (unsigned)c[0]);
            atomicMax(&packed[c[1]], ((u64)(e0 + 4) << 32) | (unsigned)c[3]);
        }
        return;
    }

    __shared__ __align__(16) unsigned short Xs[64 * 128];
    int r0 = (b - 586) * 64;

    #pragma unroll
    for (int i = 0; i < 8; ++i) {
        int idx = i * 256 + t;
        int row = idx >> 5, q = idx & 31;
        int ri = r0 + row; if (ri >= NHE) ri = NHE - 1;
        f32x4 v = *(const f32x4*)(he_emb + (long)ri * 128 + q * 4);
        bf16x4 p;
        p[0] = (short)f2bf(v[0]); p[1] = (short)f2bf(v[1]);
        p[2] = (short)f2bf(v[2]); p[3] = (short)f2bf(v[3]);
        int byte = (row * 256 + q * 8) ^ ((row & 7) << 4);
        *(bf16x4*)((char*)Xs + byte) = p;
    }
    __syncthreads();

    int lane = t & 63, w = t >> 6;
    int wm = w >> 1, wn = w & 1;
    int l15 = lane & 15, l4 = lane >> 4;

    f32x4 acc[2][4] = {};
    #pragma unroll
    for (int kc = 0; kc < 2; ++kc)
        #pragma unroll
        for (int ks = 0; ks < 2; ++ks) {
            bf16x8 a[2], bb[4];
            #pragma unroll
            for (int fm = 0; fm < 2; ++fm) {
                int row = wm * 32 + fm * 16 + l15;
                int byte = (row * 256 + kc * 128 + ks * 64 + l4 * 16) ^ ((row & 7) << 4);
                a[fm] = *(const bf16x8*)((const char*)Xs + byte);
            }
            #pragma unroll
            for (int fn = 0; fn < 4; ++fn) {
                int col = wn * 64 + fn * 16 + l15;
                bb[fn] = *(const bf16x8*)(wt + (long)col * 256 + kc * 64 + ks * 32 + l4 * 8);
            }
            #pragma unroll
            for (int fm = 0; fm < 2; ++fm)
                #pragma unroll
                for (int fn = 0; fn < 4; ++fn)
                    acc[fm][fn] = __builtin_amdgcn_mfma_f32_16x16x32_bf16(
                        bb[fn], a[fm], acc[fm][fn], 0, 0, 0);
        }

    #pragma unroll
    for (int fm = 0; fm < 2; ++fm) {
        int ri = r0 + wm * 32 + fm * 16 + l15;
        if (ri < NHE) {
            #pragma unroll
            for (int fn = 0; fn < 4; ++fn) {
                bf16x4 p;
                p[0] = (short)f2bf(acc[fm][fn][0]);
                p[1] = (short)f2bf(acc[fm][fn][1]);
                p[2] = (short)f2bf(acc[fm][fn][2]);
                p[3] = (short)f2bf(acc[fm][fn][3]);
                *(bf16x4*)(heo + (long)ri * 128 + wn * 64 + fn * 16 + l4 * 4) = p;
            }
        }
    }
}

// out = valid ? node_emb @ Wf[128:256] + heo[h] : 0.
// Persistent 3-tile pipeline: grid 521, tiles b, b+521, b+1042. B hoisted
// once per block; per tile: decode + heo-gather to regs, convert->LDS
// (alternating buf), issue NEXT tile's packed+node loads, lgkm-only
// barrier, GEMM (B from regs), store. One barrier per tile; next tile's
// global-load latency hides under current GEMM+store.
__global__ __launch_bounds__(256) void k_main(
    const float* __restrict__ node_emb,
    const u64* __restrict__ packed,
    const unsigned short* __restrict__ wt,
    const unsigned short* __restrict__ heo,
    float* __restrict__ out)
{
    __shared__ __align__(16) unsigned short Xs[2][64 * 128];  // 2 x 16KB

    int t = threadIdx.x;
    int lane = t & 63, w = t >> 6;
    int wm = w >> 1, wn = w & 1;
    int l15 = lane & 15, l4 = lane >> 4;

    // hoist B fragments: wave's 64 output cols x K=128 (bottom half of Wf)
    bf16x8 B[4][4];
    #pragma unroll
    for (int kk = 0; kk < 4; ++kk)
        #pragma unroll
        for (int fn = 0; fn < 4; ++fn) {
            int col = wn * 64 + fn * 16 + l15;
            B[kk][fn] = *(const bf16x8*)(wt + (long)col * 256 + 128 + kk * 32 + l4 * 8);
        }

    // prologue: tile0 packed + node loads
    int r0 = blockIdx.x * 64;
    u64 p = 0;
    {
        int prow = r0 + wm * 32 + (lane & 31);
        if (lane < 32 && prow < NNODES) p = packed[prow];
    }
    f32x4 nv[8];
    #pragma unroll
    for (int i = 0; i < 8; ++i) {
        int idx = i * 256 + t;
        int row = idx >> 5, q = idx & 31;
        int ri = r0 + row; if (ri >= NNODES) ri = NNODES - 1;
        nv[i] = *(const f32x4*)(node_emb + (long)ri * 128 + q * 4);
    }

    #pragma unroll
    for (int it = 0; it < 3; ++it) {
        int rb = (blockIdx.x + it * 521) * 64;
        int rnext = (blockIdx.x + (it + 1) * 521) * 64;

        // decode + within-wave redistribute + heo gather to registers
        int he16 = (int)(p & 0xffffffffull);
        int v16 = (p != 0) ? 1 : 0;
        int hrow[2], vv[2];
        hrow[0] = __shfl(he16, l15, 64);       vv[0] = __shfl(v16, l15, 64);
        hrow[1] = __shfl(he16, 16 + l15, 64);  vv[1] = __shfl(v16, 16 + l15, 64);
        bf16x4 hv[2][4];
        #pragma unroll
        for (int fm = 0; fm < 2; ++fm)
            #pragma unroll
            for (int fn = 0; fn < 4; ++fn)
                hv[fm][fn] = *(const bf16x4*)(heo + (long)hrow[fm] * 128 +
                                              wn * 64 + fn * 16 + l4 * 4);

        // node regs -> swizzled LDS (compiler waits nv arrival)
        #pragma unroll
        for (int i = 0; i < 8; ++i) {
            int idx = i * 256 + t;
            int row = idx >> 5, q = idx & 31;
            bf16x4 pk;
            pk[0] = (short)f2bf(nv[i][0]); pk[1] = (short)f2bf(nv[i][1]);
            pk[2] = (short)f2bf(nv[i][2]); pk[3] = (short)f2bf(nv[i][3]);
            int byte = (row * 256 + q * 8) ^ ((row & 7) << 4);
            *(bf16x4*)((char*)Xs[it & 1] + byte) = pk;
        }

        // issue NEXT tile's packed + node loads (hide under GEMM+store)
        if (it < 2) {
            p = 0;
            int prow = rnext + wm * 32 + (lane & 31);
            if (lane < 32 && prow < NNODES) p = packed[prow];
            #pragma unroll
            for (int i = 0; i < 8; ++i) {
                int idx = i * 256 + t;
                int row = idx >> 5, q = idx & 31;
                int ri = rnext + row; if (ri >= NNODES) ri = NNODES - 1;
                nv[i] = *(const f32x4*)(node_emb + (long)ri * 128 + q * 4);
            }
        }

        // barrier: drain LDS only; global loads stay in flight
        asm volatile("s_waitcnt lgkmcnt(0)" ::: "memory");
        __builtin_amdgcn_sched_barrier(0);
        __builtin_amdgcn_s_barrier();
        __builtin_amdgcn_sched_barrier(0);

        // GEMM (swapped operands), B from registers
        f32x4 acc[2][4] = {};
        #pragma unroll
        for (int kk = 0; kk < 4; ++kk) {
            bf16x8 a[2];
            #pragma unroll
            for (int fm = 0; fm < 2; ++fm) {
                int row = wm * 32 + fm * 16 + l15;
                int byte = (row * 256 + kk * 64 + l4 * 16) ^ ((row & 7) << 4);
                a[fm] = *(const bf16x8*)((const char*)Xs[it & 1] + byte);
            }
            #pragma unroll
            for (int fm = 0; fm < 2; ++fm)
                #pragma unroll
                for (int fn = 0; fn < 4; ++fn)
                    acc[fm][fn] = __builtin_amdgcn_mfma_f32_16x16x32_bf16(
                        B[kk][fn], a[fm], acc[fm][fn], 0, 0, 0);
        }

        // epilogue: lane owns row rb+wm*32+fm*16+l15, cols wn*64+fn*16+l4*4+(0..3)
        #pragma unroll
        for (int fm = 0; fm < 2; ++fm) {
            int ri = rb + wm * 32 + fm * 16 + l15;
            if (ri < NNODES) {
                int v = vv[fm];
                #pragma unroll
                for (int fn = 0; fn < 4; ++fn) {
                    f32x4 o;
                    #pragma unroll
                    for (int jj = 0; jj < 4; ++jj)
                        o[jj] = v ? (acc[fm][fn][jj] + bf2f((unsigned short)hv[fm][fn][jj]))
                                  : 0.0f;
                    *(f32x4*)(out + (long)ri * 128 + wn * 64 + fn * 16 + l4 * 4) = o;
                }
            }
        }
    }
}

extern "C" void kernel_launch(void* const* d_in, const int* in_sizes, int n_in,
                              void* d_out, int out_size, void* d_ws, size_t ws_size,
                              hipStream_t stream) {
    const float* node_emb = (const float*)d_in[0];
    // d_in[1] = semalink_embeddings : dead (softmax over size-1 axis -> gamma == 1)
    const float* he_emb = (const float*)d_in[2];
    const int* sl = (const int*)d_in[3];
    // d_in[4] = W_a : dead
    const float* Wf = (const float*)d_in[5];
    float* out = (float*)d_out;

    u64* packed = (u64*)d_ws;                                       // 800000 B
    unsigned short* wt = (unsigned short*)((char*)d_ws + 800000);   // 64 KB
    unsigned short* heo = (unsigned short*)((char*)d_ws + 865536);  // 5.12 MB

    k0<<<324, 256, 0, stream>>>(packed, Wf, wt);
    k1<<<586 + 313, 256, 0, stream>>>(sl, packed, he_emb, wt, heo);
    // 1563 tiles = 521 blocks x 3 pipelined tiles
    k_main<<<521, 256, 0, stream>>>(node_emb, packed, wt, heo, out);
}

// Round 14
// 68.083 us; speedup vs baseline: 1.0281x; 1.0281x over previous
//
#include <hip/hip_runtime.h>
#include <hip/hip_bf16.h>

#define NNODES 100000
#define NHE 20000
#define NEDGES 600000

typedef float f32x4 __attribute__((ext_vector_type(4)));
typedef short bf16x8 __attribute__((ext_vector_type(8)));
typedef short bf16x4 __attribute__((ext_vector_type(4)));
typedef int i32x4 __attribute__((ext_vector_type(4)));
typedef unsigned long long u64;

__device__ __forceinline__ unsigned short f2bf(float f) {
    unsigned u = __builtin_bit_cast(unsigned, f);
    u += 0x7fffu + ((u >> 16) & 1u);
    return (unsigned short)(u >> 16);
}
__device__ __forceinline__ float bf2f(unsigned short h) {
    unsigned u = ((unsigned)h) << 16;
    return __builtin_bit_cast(float, u);
}

// k0: zero packed[] with 16B stores (blocks 0..195) + wt = W_f^T bf16 [c][k]
__global__ void k0(u64* __restrict__ packed, const float* __restrict__ Wf,
                   unsigned short* __restrict__ wt) {
    int b = blockIdx.x, t = threadIdx.x;
    if (b < 196) {
        int i = b * 256 + t;
        if (i < NNODES / 2) ((f32x4*)packed)[i] = (f32x4){0.f, 0.f, 0.f, 0.f};
    } else {
        int idx = (b - 196) * 256 + t;
        int k = idx >> 7, c = idx & 127;
        wt[c * 256 + k] = f2bf(Wf[idx]);
    }
}

// k1: fused — blocks 0..585: vectorized scatter (4 edges/thread, 3x int4);
//     blocks 586..742: he-GEMM, R11-style: 2-tile pipeline + B-hoist.
//     heo[20000][128] bf16 = he_emb @ Wf[0:128]; 157 blocks x 2 tiles = 314.
__global__ __launch_bounds__(256) void k1(
    const int* __restrict__ sl, u64* __restrict__ packed,
    const float* __restrict__ he_emb, const unsigned short* __restrict__ wt,
    unsigned short* __restrict__ heo)
{
    int b = blockIdx.x, t = threadIdx.x;
    if (b < 586) {
        int tg = b * 256 + t;
        if (tg < NEDGES / 4) {
            const i32x4* s4 = (const i32x4*)sl;
            i32x4 a = s4[3 * tg], bb = s4[3 * tg + 1], c = s4[3 * tg + 2];
            int e0 = 4 * tg;
            atomicMax(&packed[a[0]], ((u64)(e0 + 1) << 32) | (unsigned)a[2]);
            atomicMax(&packed[a[3]], ((u64)(e0 + 2) << 32) | (unsigned)bb[1]);
            atomicMax(&packed[bb[2]], ((u64)(e0 + 3) << 32) | (unsigned)c[0]);
            atomicMax(&packed[c[1]], ((u64)(e0 + 4) << 32) | (unsigned)c[3]);
        }
        return;
    }

    __shared__ __align__(16) unsigned short Xs[2][64 * 128];
    int bb_ = b - 586;                        // 0..156
    int lane = t & 63, w = t >> 6;
    int wm = w >> 1, wn = w & 1;
    int l15 = lane & 15, l4 = lane >> 4;

    // hoist B: wave's 64 cols x K=128 (TOP half of Wf)
    bf16x8 B[4][4];
    #pragma unroll
    for (int kk = 0; kk < 4; ++kk)
        #pragma unroll
        for (int fn = 0; fn < 4; ++fn) {
            int col = wn * 64 + fn * 16 + l15;
            B[kk][fn] = *(const bf16x8*)(wt + (long)col * 256 + kk * 32 + l4 * 8);
        }

    int r0 = bb_ * 64;
    int r1 = (bb_ + 157) * 64;

    f32x4 nv[8];
    #pragma unroll
    for (int i = 0; i < 8; ++i) {
        int idx = i * 256 + t;
        int row = idx >> 5, q = idx & 31;
        int ri = r0 + row; if (ri >= NHE) ri = NHE - 1;
        nv[i] = *(const f32x4*)(he_emb + (long)ri * 128 + q * 4);
    }

    #pragma unroll
    for (int j = 0; j < 2; ++j) {
        int rb = j ? r1 : r0;

        #pragma unroll
        for (int i = 0; i < 8; ++i) {
            int idx = i * 256 + t;
            int row = idx >> 5, q = idx & 31;
            bf16x4 pk;
            pk[0] = (short)f2bf(nv[i][0]); pk[1] = (short)f2bf(nv[i][1]);
            pk[2] = (short)f2bf(nv[i][2]); pk[3] = (short)f2bf(nv[i][3]);
            int byte = (row * 256 + q * 8) ^ ((row & 7) << 4);
            *(bf16x4*)((char*)Xs[j] + byte) = pk;
        }

        if (j == 0) {
            #pragma unroll
            for (int i = 0; i < 8; ++i) {
                int idx = i * 256 + t;
                int row = idx >> 5, q = idx & 31;
                int ri = r1 + row; if (ri >= NHE) ri = NHE - 1;
                nv[i] = *(const f32x4*)(he_emb + (long)ri * 128 + q * 4);
            }
        }

        asm volatile("s_waitcnt lgkmcnt(0)" ::: "memory");
        __builtin_amdgcn_sched_barrier(0);
        __builtin_amdgcn_s_barrier();
        __builtin_amdgcn_sched_barrier(0);

        f32x4 acc[2][4] = {};
        #pragma unroll
        for (int kk = 0; kk < 4; ++kk) {
            bf16x8 a[2];
            #pragma unroll
            for (int fm = 0; fm < 2; ++fm) {
                int row = wm * 32 + fm * 16 + l15;
                int byte = (row * 256 + kk * 64 + l4 * 16) ^ ((row & 7) << 4);
                a[fm] = *(const bf16x8*)((const char*)Xs[j] + byte);
            }
            #pragma unroll
            for (int fm = 0; fm < 2; ++fm)
                #pragma unroll
                for (int fn = 0; fn < 4; ++fn)
                    acc[fm][fn] = __builtin_amdgcn_mfma_f32_16x16x32_bf16(
                        B[kk][fn], a[fm], acc[fm][fn], 0, 0, 0);
        }

        #pragma unroll
        for (int fm = 0; fm < 2; ++fm) {
            int ri = rb + wm * 32 + fm * 16 + l15;
            if (ri < NHE) {
                #pragma unroll
                for (int fn = 0; fn < 4; ++fn) {
                    bf16x4 p;
                    p[0] = (short)f2bf(acc[fm][fn][0]);
                    p[1] = (short)f2bf(acc[fm][fn][1]);
                    p[2] = (short)f2bf(acc[fm][fn][2]);
                    p[3] = (short)f2bf(acc[fm][fn][3]);
                    *(bf16x4*)(heo + (long)ri * 128 + wn * 64 + fn * 16 + l4 * 4) = p;
                }
            }
        }
    }
}

// out = valid ? node_emb @ Wf[128:256] + heo[h] : 0.   (R11 exact)
__global__ __launch_bounds__(256) void k_main(
    const float* __restrict__ node_emb,
    const u64* __restrict__ packed,
    const unsigned short* __restrict__ wt,
    const unsigned short* __restrict__ heo,
    float* __restrict__ out)
{
    __shared__ __align__(16) unsigned short Xs[2][64 * 128];

    int t = threadIdx.x;
    int lane = t & 63, w = t >> 6;
    int wm = w >> 1, wn = w & 1;
    int l15 = lane & 15, l4 = lane >> 4;

    bf16x8 B[4][4];
    #pragma unroll
    for (int kk = 0; kk < 4; ++kk)
        #pragma unroll
        for (int fn = 0; fn < 4; ++fn) {
            int col = wn * 64 + fn * 16 + l15;
            B[kk][fn] = *(const bf16x8*)(wt + (long)col * 256 + 128 + kk * 32 + l4 * 8);
        }

    int r0 = blockIdx.x * 64;
    int r1 = (blockIdx.x + 782) * 64;

    u64 p = 0;
    {
        int prow = r0 + wm * 32 + (lane & 31);
        if (lane < 32 && prow < NNODES) p = packed[prow];
    }
    f32x4 nv[8];
    #pragma unroll
    for (int i = 0; i < 8; ++i) {
        int idx = i * 256 + t;
        int row = idx >> 5, q = idx & 31;
        int ri = r0 + row; if (ri >= NNODES) ri = NNODES - 1;
        nv[i] = *(const f32x4*)(node_emb + (long)ri * 128 + q * 4);
    }

    #pragma unroll
    for (int j = 0; j < 2; ++j) {
        int rb = j ? r1 : r0;

        int he16 = (int)(p & 0xffffffffull);
        int v16 = (p != 0) ? 1 : 0;
        int hrow[2], vv[2];
        hrow[0] = __shfl(he16, l15, 64);       vv[0] = __shfl(v16, l15, 64);
        hrow[1] = __shfl(he16, 16 + l15, 64);  vv[1] = __shfl(v16, 16 + l15, 64);
        bf16x4 hv[2][4];
        #pragma unroll
        for (int fm = 0; fm < 2; ++fm)
            #pragma unroll
            for (int fn = 0; fn < 4; ++fn)
                hv[fm][fn] = *(const bf16x4*)(heo + (long)hrow[fm] * 128 +
                                              wn * 64 + fn * 16 + l4 * 4);

        #pragma unroll
        for (int i = 0; i < 8; ++i) {
            int idx = i * 256 + t;
            int row = idx >> 5, q = idx & 31;
            bf16x4 pk;
            pk[0] = (short)f2bf(nv[i][0]); pk[1] = (short)f2bf(nv[i][1]);
            pk[2] = (short)f2bf(nv[i][2]); pk[3] = (short)f2bf(nv[i][3]);
            int byte = (row * 256 + q * 8) ^ ((row & 7) << 4);
            *(bf16x4*)((char*)Xs[j] + byte) = pk;
        }

        if (j == 0) {
            p = 0;
            int prow = r1 + wm * 32 + (lane & 31);
            if (lane < 32 && prow < NNODES) p = packed[prow];
            #pragma unroll
            for (int i = 0; i < 8; ++i) {
                int idx = i * 256 + t;
                int row = idx >> 5, q = idx & 31;
                int ri = r1 + row; if (ri >= NNODES) ri = NNODES - 1;
                nv[i] = *(const f32x4*)(node_emb + (long)ri * 128 + q * 4);
            }
        }

        asm volatile("s_waitcnt lgkmcnt(0)" ::: "memory");
        __builtin_amdgcn_sched_barrier(0);
        __builtin_amdgcn_s_barrier();
        __builtin_amdgcn_sched_barrier(0);

        f32x4 acc[2][4] = {};
        #pragma unroll
        for (int kk = 0; kk < 4; ++kk) {
            bf16x8 a[2];
            #pragma unroll
            for (int fm = 0; fm < 2; ++fm) {
                int row = wm * 32 + fm * 16 + l15;
                int byte = (row * 256 + kk * 64 + l4 * 16) ^ ((row & 7) << 4);
                a[fm] = *(const bf16x8*)((const char*)Xs[j] + byte);
            }
            #pragma unroll
            for (int fm = 0; fm < 2; ++fm)
                #pragma unroll
                for (int fn = 0; fn < 4; ++fn)
                    acc[fm][fn] = __builtin_amdgcn_mfma_f32_16x16x32_bf16(
                        B[kk][fn], a[fm], acc[fm][fn], 0, 0, 0);
        }

        #pragma unroll
        for (int fm = 0; fm < 2; ++fm) {
            int ri = rb + wm * 32 + fm * 16 + l15;
            if (ri < NNODES) {
                int v = vv[fm];
                #pragma unroll
                for (int fn = 0; fn < 4; ++fn) {
                    f32x4 o;
                    #pragma unroll
                    for (int jj = 0; jj < 4; ++jj)
                        o[jj] = v ? (acc[fm][fn][jj] + bf2f((unsigned short)hv[fm][fn][jj]))
                                  : 0.0f;
                    *(f32x4*)(out + (long)ri * 128 + wn * 64 + fn * 16 + l4 * 4) = o;
                }
            }
        }
    }
}

extern "C" void kernel_launch(void* const* d_in, const int* in_sizes, int n_in,
                              void* d_out, int out_size, void* d_ws, size_t ws_size,
                              hipStream_t stream) {
    const float* node_emb = (const float*)d_in[0];
    // d_in[1] = semalink_embeddings : dead (softmax over size-1 axis -> gamma == 1)
    const float* he_emb = (const float*)d_in[2];
    const int* sl = (const int*)d_in[3];
    // d_in[4] = W_a : dead
    const float* Wf = (const float*)d_in[5];
    float* out = (float*)d_out;

    u64* packed = (u64*)d_ws;                                       // 800000 B
    unsigned short* wt = (unsigned short*)((char*)d_ws + 800000);   // 64 KB
    unsigned short* heo = (unsigned short*)((char*)d_ws + 865536);  // 5.12 MB

    k0<<<324, 256, 0, stream>>>(packed, Wf, wt);
    k1<<<586 + 157, 256, 0, stream>>>(sl, packed, he_emb, wt, heo);
    k_main<<<782, 256, 0, stream>>>(node_emb, packed, wt, heo, out);
}